// Round 2
// baseline (449.190 us; speedup 1.0000x reference)
//
#include <hip/hip_runtime.h>
#include <hip/hip_bf16.h>
#include <cstdint>
#include <cstddef>

// Problem: B=4, LQ=LK=1024, D=512, H=8. Inputs/outputs fp32 on device;
// compute in bf16 MFMA (2%-of-max absmax threshold gives plenty of room).

typedef __bf16 bf16;
typedef __bf16 bf16x4 __attribute__((ext_vector_type(4)));
typedef __bf16 bf16x8 __attribute__((ext_vector_type(8)));
typedef float f32x4 __attribute__((ext_vector_type(4)));

__device__ inline void gload_lds16(const void* g, void* l) {
  __builtin_amdgcn_global_load_lds(
      (const __attribute__((address_space(1))) void*)g,
      (__attribute__((address_space(3))) void*)l, 16, 0, 0);
}

__device__ inline float bf2f(unsigned short u) {
  union { unsigned u32; float f; } cvt;
  cvt.u32 = ((unsigned)u) << 16;
  return cvt.f;
}
__device__ inline unsigned short f2bfu(float f) {
  union { bf16 h; unsigned short u; } cvt;
  cvt.h = (bf16)f;
  return cvt.u;
}

// Convert six fp32 tensors (2M elements each) to bf16. grid: (2048, 6).
__global__ __launch_bounds__(256) void cvt6(
    const float* __restrict__ s0, const float* __restrict__ s1,
    const float* __restrict__ s2, const float* __restrict__ s3,
    const float* __restrict__ s4, const float* __restrict__ s5,
    bf16* __restrict__ d0, bf16* __restrict__ d1, bf16* __restrict__ d2,
    bf16* __restrict__ d3, bf16* __restrict__ d4, bf16* __restrict__ d5)
{
  const float* s; bf16* d;
  switch (blockIdx.y) {
    case 0: s = s0; d = d0; break;
    case 1: s = s1; d = d1; break;
    case 2: s = s2; d = d2; break;
    case 3: s = s3; d = d3; break;
    case 4: s = s4; d = d4; break;
    default: s = s5; d = d5; break;
  }
  const int i = (blockIdx.x * 256 + threadIdx.x) * 4;
  float4 v = *(const float4*)(s + i);
  bf16x4 o;
  o[0] = (bf16)v.x; o[1] = (bf16)v.y; o[2] = (bf16)v.z; o[3] = (bf16)v.w;
  *(bf16x4*)(d + i) = o;
}

// C[M,N] = scale * (A[M,K] . B[N,K]^T), bf16 in, CT out, fp32 accum.
// Batched over gridDim.z with z = b*8 + h; per-operand strides for b and h.
// 128x128 tile, BK=32, 256 threads (4 waves, each 64x64 of 16x16x32 mfma).
template <typename CT>
__global__ __launch_bounds__(256) void gemm_nt(
    const bf16* __restrict__ A, const bf16* __restrict__ B, CT* __restrict__ C,
    int K, int lda, int ldb, int ldc,
    long ab, long ah, long bbs, long bh, long cb, long ch, float scale)
{
  __shared__ bf16 As[128 * 32];
  __shared__ bf16 Bs[128 * 32];
  const int z = blockIdx.z;
  const int zb = z >> 3, zh = z & 7;
  A += (size_t)zb * ab + (size_t)zh * ah;
  B += (size_t)zb * bbs + (size_t)zh * bh;
  C += (size_t)zb * cb + (size_t)zh * ch;
  const int m0 = blockIdx.y * 128, n0 = blockIdx.x * 128;
  const int t = threadIdx.x;
  const int lane = t & 63, w = t >> 6;
  const int wm = w >> 1, wn = w & 1;

  // staging: 4 lanes per row (4 x 8 bf16 = 32 cols), 64 rows per issue, 2 issues.
  const int srow = t >> 2;
  const int scol = (t & 3) << 3;
  const bf16* Ag = A + (size_t)(m0 + srow) * lda + scol;
  const bf16* Bg = B + (size_t)(n0 + srow) * ldb + scol;
  bf16* Als = As + t * 8;   // lds dest = wave-uniform base + lane*16B
  bf16* Bls = Bs + t * 8;

  f32x4 acc[4][4] = {};
  const int kq = (lane >> 4) << 3;   // k-chunk within BK=32
  const int rr = lane & 15;

  const int kIters = K >> 5;
  for (int kt = 0; kt < kIters; ++kt) {
    __syncthreads();
    gload_lds16(Ag, Als);
    gload_lds16(Ag + 64 * (size_t)lda, Als + 2048);
    gload_lds16(Bg, Bls);
    gload_lds16(Bg + 64 * (size_t)ldb, Bls + 2048);
    Ag += 32; Bg += 32;
    __syncthreads();

    bf16x8 af[4], bfr[4];
#pragma unroll
    for (int r = 0; r < 4; ++r)
      af[r] = *(const bf16x8*)(As + ((wm * 64 + r * 16 + rr) * 32 + kq));
#pragma unroll
    for (int c = 0; c < 4; ++c)
      bfr[c] = *(const bf16x8*)(Bs + ((wn * 64 + c * 16 + rr) * 32 + kq));
#pragma unroll
    for (int r = 0; r < 4; ++r)
#pragma unroll
      for (int c = 0; c < 4; ++c)
        acc[r][c] = __builtin_amdgcn_mfma_f32_16x16x32_bf16(af[r], bfr[c], acc[r][c], 0, 0, 0);
  }

  // C/D frag: col = lane&15, row = (lane>>4)*4 + reg
  const int cr0 = (lane >> 4) << 2;
  const int cc = lane & 15;
#pragma unroll
  for (int r = 0; r < 4; ++r) {
#pragma unroll
    for (int c = 0; c < 4; ++c) {
      const int gr = m0 + wm * 64 + r * 16 + cr0;
      const int gc = n0 + wn * 64 + c * 16 + cc;
#pragma unroll
      for (int i = 0; i < 4; ++i)
        C[(size_t)(gr + i) * ldc + gc] = (CT)(acc[r][c][i] * scale);
    }
  }
}

// In-place masked softmax over rows of S [B*H*L, 1024] (bf16), mask [B,L,1024] i32.
__global__ __launch_bounds__(256) void softmax_rows(
    bf16* __restrict__ S, const int* __restrict__ mask)
{
  const int row = blockIdx.x;          // b*8192 + h*1024 + l
  const int b = row >> 13;
  const int l = row & 1023;
  unsigned short* srow = (unsigned short*)(S + (size_t)row * 1024);
  const int* mrow = mask + (((size_t)b << 10) + l) * 1024;
  const int t = threadIdx.x;
  const int lane = t & 63, w = t >> 6;

  ushort4 raw = *(const ushort4*)(srow + t * 4);
  int4 mk = *(const int4*)(mrow + t * 4);
  float v0 = mk.x ? bf2f(raw.x) : -__builtin_inff();
  float v1 = mk.y ? bf2f(raw.y) : -__builtin_inff();
  float v2 = mk.z ? bf2f(raw.z) : -__builtin_inff();
  float v3 = mk.w ? bf2f(raw.w) : -__builtin_inff();

  float mx = fmaxf(fmaxf(v0, v1), fmaxf(v2, v3));
#pragma unroll
  for (int off = 32; off > 0; off >>= 1) mx = fmaxf(mx, __shfl_xor(mx, off));
  __shared__ float red[8];
  if (lane == 0) red[w] = mx;
  __syncthreads();
  mx = fmaxf(fmaxf(red[0], red[1]), fmaxf(red[2], red[3]));

  float e0 = __expf(v0 - mx), e1 = __expf(v1 - mx);
  float e2 = __expf(v2 - mx), e3 = __expf(v3 - mx);
  float s = (e0 + e1) + (e2 + e3);
#pragma unroll
  for (int off = 32; off > 0; off >>= 1) s += __shfl_xor(s, off);
  if (lane == 0) red[4 + w] = s;
  __syncthreads();
  s = (red[4] + red[5]) + (red[6] + red[7]);
  float inv = 1.0f / s;

  ushort4 o;
  o.x = f2bfu(e0 * inv); o.y = f2bfu(e1 * inv);
  o.z = f2bfu(e2 * inv); o.w = f2bfu(e3 * inv);
  *(ushort4*)(srow + t * 4) = o;
}

extern "C" void kernel_launch(void* const* d_in, const int* in_sizes, int n_in,
                              void* d_out, int out_size, void* d_ws, size_t ws_size,
                              hipStream_t stream) {
  const float* x    = (const float*)d_in[0];   // [4,1024,512]
  const float* st   = (const float*)d_in[1];   // [4,1024,512]
  const int*   mask = (const int*)d_in[2];     // [4,1024,1024]
  const float* Wq   = (const float*)d_in[3];   // [8,512,512]
  const float* Wk   = (const float*)d_in[4];
  const float* Wv   = (const float*)d_in[5];
  const float* Wp   = (const float*)d_in[6];   // [512,4096]
  float* out = (float*)d_out;                  // [4,1024,512] fp32

  char* ws = (char*)d_ws;
  const size_t MB = 1048576;
  bf16* xb  = (bf16*)(ws);              // 4MB  (2M bf16)
  bf16* stb = (bf16*)(ws + 4 * MB);     // 4MB
  bf16* wqb = (bf16*)(ws + 8 * MB);     // 4MB
  bf16* wkb = (bf16*)(ws + 12 * MB);    // 4MB
  bf16* wvb = (bf16*)(ws + 16 * MB);    // 4MB
  bf16* wpb = (bf16*)(ws + 20 * MB);    // 4MB
  bf16* q   = (bf16*)(ws + 24 * MB);    // [4,8,1024,512]  32MB
  bf16* k   = (bf16*)(ws + 56 * MB);    // [4,8,1024,512]  32MB
  bf16* vT  = (bf16*)(ws + 88 * MB);    // [4,8,512,1024]  32MB
  bf16* sc  = (bf16*)(ws + 120 * MB);   // [4,8,1024,1024] 64MB (scores->attn)
  bf16* ctx = (bf16*)(ws + 24 * MB);    // [4,1024,4096]   32MB (reuses q; q dead)

  dim3 blk(256);
  const float scale = 0.04419417382415922f;  // 1/sqrt(512)

  // fp32 -> bf16 conversions (all six tensors are exactly 2M elements)
  cvt6<<<dim3(2048, 6), blk, 0, stream>>>(x, st, Wq, Wk, Wv, Wp,
                                          xb, stb, wqb, wkb, wvb, wpb);

  // q[b,h,l,e] = x[b] @ Wq[h]^T   (M=1024,N=512,K=512)
  gemm_nt<bf16><<<dim3(4, 8, 32), blk, 0, stream>>>(xb, wqb, q, 512, 512, 512, 512,
      524288L, 0L, 0L, 262144L, 4194304L, 524288L, 1.0f);
  // k[b,h,s,e] = states[b] @ Wk[h]^T
  gemm_nt<bf16><<<dim3(4, 8, 32), blk, 0, stream>>>(stb, wkb, k, 512, 512, 512, 512,
      524288L, 0L, 0L, 262144L, 4194304L, 524288L, 1.0f);
  // vT[b,h,e,s] = Wv[h] @ states[b]^T   (M=512,N=1024,K=512)
  gemm_nt<bf16><<<dim3(8, 4, 32), blk, 0, stream>>>(wvb, stb, vT, 512, 512, 512, 1024,
      0L, 262144L, 524288L, 0L, 4194304L, 524288L, 1.0f);
  // scores[b,h,l,s] = scale * q[b,h] @ k[b,h]^T   (M=1024,N=1024,K=512)
  gemm_nt<bf16><<<dim3(8, 8, 32), blk, 0, stream>>>(q, k, sc, 512, 512, 512, 1024,
      4194304L, 524288L, 4194304L, 524288L, 8388608L, 1048576L, scale);
  // attn = softmax(scores) in place
  softmax_rows<<<dim3(32768), blk, 0, stream>>>(sc, mask);
  // ctx[b,l,h*512+e] = attn[b,h] @ v[b,h]   (M=1024,N=512,K=1024; B op = vT)
  gemm_nt<bf16><<<dim3(4, 8, 32), blk, 0, stream>>>(sc, vT, ctx, 1024, 1024, 1024, 4096,
      8388608L, 1048576L, 4194304L, 524288L, 4194304L, 512L, 1.0f);
  // out[b*l, e] = ctx @ Wp^T   (M=4096,N=512,K=4096) -> fp32
  gemm_nt<float><<<dim3(4, 32, 1), blk, 0, stream>>>(ctx, wpb, out, 4096, 4096, 4096, 512,
      0L, 0L, 0L, 0L, 0L, 0L, 1.0f);
}

// Round 3
// 414.822 us; speedup vs baseline: 1.0829x; 1.0829x over previous
//
#include <hip/hip_runtime.h>
#include <hip/hip_bf16.h>
#include <cstdint>
#include <cstddef>

// B=4, LQ=LK=1024, D=512, H=8. fp32 in/out; bf16 MFMA compute.
// R3: split-K out-projection (atomic fp32) + XOR-swizzled LDS (kill 8-way conflicts).

typedef __bf16 bf16;
typedef __bf16 bf16x4 __attribute__((ext_vector_type(4)));
typedef __bf16 bf16x8 __attribute__((ext_vector_type(8)));
typedef float f32x4 __attribute__((ext_vector_type(4)));

__device__ inline void gload_lds16(const void* g, void* l) {
  __builtin_amdgcn_global_load_lds(
      (const __attribute__((address_space(1))) void*)g,
      (__attribute__((address_space(3))) void*)l, 16, 0, 0);
}

__device__ inline float bf2f(unsigned short u) {
  union { unsigned u32; float f; } cvt;
  cvt.u32 = ((unsigned)u) << 16;
  return cvt.f;
}
__device__ inline unsigned short f2bfu(float f) {
  union { bf16 h; unsigned short u; } cvt;
  cvt.h = (bf16)f;
  return cvt.u;
}

// Convert six fp32 tensors (2M elements each) to bf16. grid: (2048, 6).
__global__ __launch_bounds__(256) void cvt6(
    const float* __restrict__ s0, const float* __restrict__ s1,
    const float* __restrict__ s2, const float* __restrict__ s3,
    const float* __restrict__ s4, const float* __restrict__ s5,
    bf16* __restrict__ d0, bf16* __restrict__ d1, bf16* __restrict__ d2,
    bf16* __restrict__ d3, bf16* __restrict__ d4, bf16* __restrict__ d5)
{
  const float* s; bf16* d;
  switch (blockIdx.y) {
    case 0: s = s0; d = d0; break;
    case 1: s = s1; d = d1; break;
    case 2: s = s2; d = d2; break;
    case 3: s = s3; d = d3; break;
    case 4: s = s4; d = d4; break;
    default: s = s5; d = d5; break;
  }
  const int i = (blockIdx.x * 256 + threadIdx.x) * 4;
  float4 v = *(const float4*)(s + i);
  bf16x4 o;
  o[0] = (bf16)v.x; o[1] = (bf16)v.y; o[2] = (bf16)v.z; o[3] = (bf16)v.w;
  *(bf16x4*)(d + i) = o;
}

// C[M,N] = scale * (A[M,K] . B[N,K]^T), bf16 in, CT out, fp32 accum.
// Batched over gridDim.z with z = b*8 + h; per-operand strides for b and h.
// 128x128 tile, BK=32, 256 threads (4 waves, each 64x64 of 16x16x32 mfma).
// LDS chunk-XOR swizzle: global 16B-chunk c of row r lives at slot c ^ ((r>>1)&3).
template <typename CT, bool ATOMIC>
__global__ __launch_bounds__(256) void gemm_nt(
    const bf16* __restrict__ A, const bf16* __restrict__ B, CT* __restrict__ C,
    int K, int lda, int ldb, int ldc,
    long ab, long ah, long bbs, long bh, long cb, long ch, float scale)
{
  __shared__ bf16 As[128 * 32];
  __shared__ bf16 Bs[128 * 32];
  const int z = blockIdx.z;
  const int zb = z >> 3, zh = z & 7;
  A += (size_t)zb * ab + (size_t)zh * ah;
  B += (size_t)zb * bbs + (size_t)zh * bh;
  C += (size_t)zb * cb + (size_t)zh * ch;
  const int m0 = blockIdx.y * 128, n0 = blockIdx.x * 128;
  const int t = threadIdx.x;
  const int lane = t & 63, w = t >> 6;
  const int wm = w >> 1, wn = w & 1;

  // staging: 4 lanes per row (4 x 8 bf16 = 32 cols), 64 rows per issue, 2 issues.
  // lane t loads global chunk (t&3)^((srow>>1)&3) into linear LDS slot t*8.
  const int srow = t >> 2;
  const int schunk = (t & 3) ^ ((srow >> 1) & 3);
  const bf16* Ag = A + (size_t)(m0 + srow) * lda + schunk * 8;
  const bf16* Bg = B + (size_t)(n0 + srow) * ldb + schunk * 8;
  bf16* Als = As + t * 8;   // lds dest = wave-uniform base + lane*16B
  bf16* Bls = Bs + t * 8;

  f32x4 acc[4][4] = {};
  const int rr = lane & 15;
  const int kqs = ((lane >> 4) ^ ((rr >> 1) & 3)) << 3;  // swizzled k-chunk offset

  const int kIters = K >> 5;
  for (int kt = 0; kt < kIters; ++kt) {
    __syncthreads();
    gload_lds16(Ag, Als);
    gload_lds16(Ag + 64 * (size_t)lda, Als + 2048);
    gload_lds16(Bg, Bls);
    gload_lds16(Bg + 64 * (size_t)ldb, Bls + 2048);
    Ag += 32; Bg += 32;
    __syncthreads();

    bf16x8 af[4], bfr[4];
#pragma unroll
    for (int r = 0; r < 4; ++r)
      af[r] = *(const bf16x8*)(As + ((wm * 64 + r * 16 + rr) * 32 + kqs));
#pragma unroll
    for (int c = 0; c < 4; ++c)
      bfr[c] = *(const bf16x8*)(Bs + ((wn * 64 + c * 16 + rr) * 32 + kqs));
#pragma unroll
    for (int r = 0; r < 4; ++r)
#pragma unroll
      for (int c = 0; c < 4; ++c)
        acc[r][c] = __builtin_amdgcn_mfma_f32_16x16x32_bf16(af[r], bfr[c], acc[r][c], 0, 0, 0);
  }

  // C/D frag: col = lane&15, row = (lane>>4)*4 + reg
  const int cr0 = (lane >> 4) << 2;
  const int cc = lane & 15;
#pragma unroll
  for (int r = 0; r < 4; ++r) {
#pragma unroll
    for (int c = 0; c < 4; ++c) {
      const int gr = m0 + wm * 64 + r * 16 + cr0;
      const int gc = n0 + wn * 64 + c * 16 + cc;
#pragma unroll
      for (int i = 0; i < 4; ++i) {
        if (ATOMIC)
          atomicAdd((float*)&C[(size_t)(gr + i) * ldc + gc], acc[r][c][i] * scale);
        else
          C[(size_t)(gr + i) * ldc + gc] = (CT)(acc[r][c][i] * scale);
      }
    }
  }
}

// In-place masked softmax over rows of S [B*H*L, 1024] (bf16), mask [B,L,1024] i32.
__global__ __launch_bounds__(256) void softmax_rows(
    bf16* __restrict__ S, const int* __restrict__ mask)
{
  const int row = blockIdx.x;          // b*8192 + h*1024 + l
  const int b = row >> 13;
  const int l = row & 1023;
  unsigned short* srow = (unsigned short*)(S + (size_t)row * 1024);
  const int* mrow = mask + (((size_t)b << 10) + l) * 1024;
  const int t = threadIdx.x;
  const int lane = t & 63, w = t >> 6;

  ushort4 raw = *(const ushort4*)(srow + t * 4);
  int4 mk = *(const int4*)(mrow + t * 4);
  float v0 = mk.x ? bf2f(raw.x) : -__builtin_inff();
  float v1 = mk.y ? bf2f(raw.y) : -__builtin_inff();
  float v2 = mk.z ? bf2f(raw.z) : -__builtin_inff();
  float v3 = mk.w ? bf2f(raw.w) : -__builtin_inff();

  float mx = fmaxf(fmaxf(v0, v1), fmaxf(v2, v3));
#pragma unroll
  for (int off = 32; off > 0; off >>= 1) mx = fmaxf(mx, __shfl_xor(mx, off));
  __shared__ float red[8];
  if (lane == 0) red[w] = mx;
  __syncthreads();
  mx = fmaxf(fmaxf(red[0], red[1]), fmaxf(red[2], red[3]));

  float e0 = __expf(v0 - mx), e1 = __expf(v1 - mx);
  float e2 = __expf(v2 - mx), e3 = __expf(v3 - mx);
  float s = (e0 + e1) + (e2 + e3);
#pragma unroll
  for (int off = 32; off > 0; off >>= 1) s += __shfl_xor(s, off);
  if (lane == 0) red[4 + w] = s;
  __syncthreads();
  s = (red[4] + red[5]) + (red[6] + red[7]);
  float inv = 1.0f / s;

  ushort4 o;
  o.x = f2bfu(e0 * inv); o.y = f2bfu(e1 * inv);
  o.z = f2bfu(e2 * inv); o.w = f2bfu(e3 * inv);
  *(ushort4*)(srow + t * 4) = o;
}

extern "C" void kernel_launch(void* const* d_in, const int* in_sizes, int n_in,
                              void* d_out, int out_size, void* d_ws, size_t ws_size,
                              hipStream_t stream) {
  const float* x    = (const float*)d_in[0];   // [4,1024,512]
  const float* st   = (const float*)d_in[1];   // [4,1024,512]
  const int*   mask = (const int*)d_in[2];     // [4,1024,1024]
  const float* Wq   = (const float*)d_in[3];   // [8,512,512]
  const float* Wk   = (const float*)d_in[4];
  const float* Wv   = (const float*)d_in[5];
  const float* Wp   = (const float*)d_in[6];   // [512,4096]
  float* out = (float*)d_out;                  // [4,1024,512] fp32

  char* ws = (char*)d_ws;
  const size_t MB = 1048576;
  bf16* xb  = (bf16*)(ws);              // 4MB  (2M bf16)
  bf16* stb = (bf16*)(ws + 4 * MB);     // 4MB
  bf16* wqb = (bf16*)(ws + 8 * MB);     // 4MB
  bf16* wkb = (bf16*)(ws + 12 * MB);    // 4MB
  bf16* wvb = (bf16*)(ws + 16 * MB);    // 4MB
  bf16* wpb = (bf16*)(ws + 20 * MB);    // 4MB
  bf16* q   = (bf16*)(ws + 24 * MB);    // [4,8,1024,512]  32MB
  bf16* k   = (bf16*)(ws + 56 * MB);    // [4,8,1024,512]  32MB
  bf16* vT  = (bf16*)(ws + 88 * MB);    // [4,8,512,1024]  32MB
  bf16* sc  = (bf16*)(ws + 120 * MB);   // [4,8,1024,1024] 64MB (scores->attn)
  bf16* ctx = (bf16*)(ws + 24 * MB);    // [4,1024,4096]   32MB (reuses q; q dead)

  dim3 blk(256);
  const float scale = 0.04419417382415922f;  // 1/sqrt(512)

  // fp32 -> bf16 conversions (all six tensors are exactly 2M elements)
  cvt6<<<dim3(2048, 6), blk, 0, stream>>>(x, st, Wq, Wk, Wv, Wp,
                                          xb, stb, wqb, wkb, wvb, wpb);

  // q[b,h,l,e] = x[b] @ Wq[h]^T   (M=1024,N=512,K=512)
  gemm_nt<bf16, false><<<dim3(4, 8, 32), blk, 0, stream>>>(xb, wqb, q, 512, 512, 512, 512,
      524288L, 0L, 0L, 262144L, 4194304L, 524288L, 1.0f);
  // k[b,h,s,e] = states[b] @ Wk[h]^T
  gemm_nt<bf16, false><<<dim3(4, 8, 32), blk, 0, stream>>>(stb, wkb, k, 512, 512, 512, 512,
      524288L, 0L, 0L, 262144L, 4194304L, 524288L, 1.0f);
  // vT[b,h,e,s] = Wv[h] @ states[b]^T   (M=512,N=1024,K=512)
  gemm_nt<bf16, false><<<dim3(8, 4, 32), blk, 0, stream>>>(wvb, stb, vT, 512, 512, 512, 1024,
      0L, 262144L, 524288L, 0L, 4194304L, 524288L, 1.0f);
  // scores[b,h,l,s] = scale * q[b,h] @ k[b,h]^T   (M=1024,N=1024,K=512)
  gemm_nt<bf16, false><<<dim3(8, 8, 32), blk, 0, stream>>>(q, k, sc, 512, 512, 512, 1024,
      4194304L, 524288L, 4194304L, 524288L, 8388608L, 1048576L, scale);
  // attn = softmax(scores) in place
  softmax_rows<<<dim3(32768), blk, 0, stream>>>(sc, mask);
  // ctx[b,l,h*512+e] = attn[b,h] @ v[b,h]   (M=1024,N=512,K=1024; B op = vT)
  gemm_nt<bf16, false><<<dim3(4, 8, 32), blk, 0, stream>>>(sc, vT, ctx, 1024, 1024, 1024, 4096,
      8388608L, 1048576L, 4194304L, 524288L, 4194304L, 512L, 1.0f);
  // out[b*l, e] = ctx @ Wp^T   (M=4096,N=512,K=4096) -> fp32, split-K=4 via atomics
  hipMemsetAsync(d_out, 0, (size_t)out_size * sizeof(float), stream);
  gemm_nt<float, true><<<dim3(4, 32, 4), blk, 0, stream>>>(ctx, wpb, out, 1024, 4096, 4096, 512,
      0L, 1024L, 0L, 1024L, 0L, 0L, 1.0f);
}

// Round 4
// 346.111 us; speedup vs baseline: 1.2978x; 1.1985x over previous
//
#include <hip/hip_runtime.h>
#include <hip/hip_bf16.h>
#include <cstdint>
#include <cstddef>

// B=4, LQ=LK=1024, D=512, H=8. fp32 in/out; bf16 MFMA compute.
// R4: BK=64 (32 MFMA/barrier), exp fused into scores epilogue (no-max softmax,
// scores ~N(0,1)), rowsum kernel + normalization in ctx epilogue, split-K
// out-proj via fp32 partials + reduce, fused QKV dispatch.

typedef __bf16 bf16;
typedef __bf16 bf16x4 __attribute__((ext_vector_type(4)));
typedef __bf16 bf16x8 __attribute__((ext_vector_type(8)));
typedef float f32x4 __attribute__((ext_vector_type(4)));

__device__ inline void gload_lds16(const void* g, void* l) {
  __builtin_amdgcn_global_load_lds(
      (const __attribute__((address_space(1))) void*)g,
      (__attribute__((address_space(3))) void*)l, 16, 0, 0);
}

__device__ inline float bf2f(unsigned short u) {
  union { unsigned u32; float f; } cvt;
  cvt.u32 = ((unsigned)u) << 16;
  return cvt.f;
}

// Convert six fp32 tensors (2M elements each) to bf16. grid: (2048, 6).
__global__ __launch_bounds__(256) void cvt6(
    const float* __restrict__ s0, const float* __restrict__ s1,
    const float* __restrict__ s2, const float* __restrict__ s3,
    const float* __restrict__ s4, const float* __restrict__ s5,
    bf16* __restrict__ d0, bf16* __restrict__ d1, bf16* __restrict__ d2,
    bf16* __restrict__ d3, bf16* __restrict__ d4, bf16* __restrict__ d5)
{
  const float* s; bf16* d;
  switch (blockIdx.y) {
    case 0: s = s0; d = d0; break;
    case 1: s = s1; d = d1; break;
    case 2: s = s2; d = d2; break;
    case 3: s = s3; d = d3; break;
    case 4: s = s4; d = d4; break;
    default: s = s5; d = d5; break;
  }
  const int i = (blockIdx.x * 256 + threadIdx.x) * 4;
  float4 v = *(const float4*)(s + i);
  bf16x4 o;
  o[0] = (bf16)v.x; o[1] = (bf16)v.y; o[2] = (bf16)v.z; o[3] = (bf16)v.w;
  *(bf16x4*)(d + i) = o;
}

// Tile body: C[128,128] tile at (m0,n0) of scale*(A . B^T). BK=64, 256 thr.
// LDS swizzle: global 16B-chunk c of row r lives at slot c ^ (r&7) (2-way, free).
// MODE 0: C = acc*scale.  MODE 1: C = mask ? exp(acc*scale) : 0 (bf16).
// MODE 2: C = acc * sinv[row] (bf16).
template <typename CT, int MODE>
__device__ __forceinline__ void gemm_body(
    bf16* As, bf16* Bs,
    const bf16* __restrict__ A, const bf16* __restrict__ B, CT* __restrict__ C,
    int K, int lda, int ldb, int ldc, int m0, int n0, float scale,
    const int* __restrict__ mrow, const float* __restrict__ sv)
{
  const int t = threadIdx.x;
  const int lane = t & 63, w = t >> 6;
  const int wm = w >> 1, wn = w & 1;

  // staging: 8 lanes per row (8 x 16B = 64 cols), 32 rows per issue, 4 issues.
  const int srow = t >> 3;                       // 0..31
  const int schunk = (t & 7) ^ (srow & 7);       // swizzled source chunk
  const bf16* Ag = A + (size_t)(m0 + srow) * lda + schunk * 8;
  const bf16* Bg = B + (size_t)(n0 + srow) * ldb + schunk * 8;
  bf16* Als = As + t * 8;   // dest = wave-uniform base + lane*16B
  bf16* Bls = Bs + t * 8;

  f32x4 acc[4][4] = {};
  const int rr = lane & 15;
  const int q4 = lane >> 4;

  const int kIters = K >> 6;
  for (int kt = 0; kt < kIters; ++kt) {
    __syncthreads();
#pragma unroll
    for (int i = 0; i < 4; ++i) {
      gload_lds16(Ag + (size_t)(32 * i) * lda, Als + i * 2048);
      gload_lds16(Bg + (size_t)(32 * i) * ldb, Bls + i * 2048);
    }
    Ag += 64; Bg += 64;
    __syncthreads();

#pragma unroll
    for (int h = 0; h < 2; ++h) {
      bf16x8 af[4], bfr[4];
      const int c = h * 4 + q4;                  // global k-chunk within BK=64
#pragma unroll
      for (int r = 0; r < 4; ++r) {
        const int R = wm * 64 + r * 16 + rr;
        af[r] = *(const bf16x8*)(As + R * 64 + ((c ^ (R & 7)) << 3));
      }
#pragma unroll
      for (int cc2 = 0; cc2 < 4; ++cc2) {
        const int R = wn * 64 + cc2 * 16 + rr;
        bfr[cc2] = *(const bf16x8*)(Bs + R * 64 + ((c ^ (R & 7)) << 3));
      }
#pragma unroll
      for (int r = 0; r < 4; ++r)
#pragma unroll
        for (int cc2 = 0; cc2 < 4; ++cc2)
          acc[r][cc2] = __builtin_amdgcn_mfma_f32_16x16x32_bf16(af[r], bfr[cc2], acc[r][cc2], 0, 0, 0);
    }
  }

  // C/D frag: col = lane&15, row = (lane>>4)*4 + reg
  const int cr0 = q4 << 2;
  const int cc = rr;
#pragma unroll
  for (int r = 0; r < 4; ++r) {
#pragma unroll
    for (int c = 0; c < 4; ++c) {
      const int gr0 = m0 + wm * 64 + r * 16 + cr0;
      const int gc = n0 + wn * 64 + c * 16 + cc;
#pragma unroll
      for (int i = 0; i < 4; ++i) {
        const int gr = gr0 + i;
        float v = acc[r][c][i];
        if (MODE == 0) {
          C[(size_t)gr * ldc + gc] = (CT)(v * scale);
        } else if (MODE == 1) {
          const int m = mrow[((size_t)gr << 10) + gc];
          C[(size_t)gr * ldc + gc] = (CT)(m ? __expf(v * scale) : 0.0f);
        } else {
          C[(size_t)gr * ldc + gc] = (CT)(v * sv[gr]);
        }
      }
    }
  }
}

// Generic batched NT GEMM: z = b*8+h with per-operand b/h strides.
template <typename CT, int MODE>
__global__ __launch_bounds__(256) void gemm_nt(
    const bf16* __restrict__ A, const bf16* __restrict__ B, CT* __restrict__ C,
    int K, int lda, int ldb, int ldc,
    long ab, long ah, long bbs, long bh, long cb, long ch, float scale,
    const int* __restrict__ mask, const float* __restrict__ sinv)
{
  __shared__ bf16 As[128 * 64];
  __shared__ bf16 Bs[128 * 64];
  const int z = blockIdx.z;
  const int zb = z >> 3, zh = z & 7;
  A += (size_t)zb * ab + (size_t)zh * ah;
  B += (size_t)zb * bbs + (size_t)zh * bh;
  C += (size_t)zb * cb + (size_t)zh * ch;
  const int* mrow = (MODE == 1) ? mask + ((size_t)zb << 20) : nullptr;
  const float* sv = (MODE == 2) ? sinv + ((size_t)z << 10) : nullptr;
  gemm_body<CT, MODE>(As, Bs, A, B, C, K, lda, ldb, ldc,
                      blockIdx.y * 128, blockIdx.x * 128, scale, mrow, sv);
}

// Fused q/k/vT projections. grid (32 tiles, 32 z, 3 jobs).
__global__ __launch_bounds__(256) void qkv_kernel(
    const bf16* __restrict__ xb, const bf16* __restrict__ stb,
    const bf16* __restrict__ wqb, const bf16* __restrict__ wkb,
    const bf16* __restrict__ wvb,
    bf16* __restrict__ q, bf16* __restrict__ k, bf16* __restrict__ vT)
{
  __shared__ bf16 As[128 * 64];
  __shared__ bf16 Bs[128 * 64];
  const int tile = blockIdx.x;
  const int zz = blockIdx.y;
  const int job = blockIdx.z;
  const size_t zb = zz >> 3, zh = zz & 7;
  if (job == 0) {
    gemm_body<bf16, 0>(As, Bs, xb + zb * 524288, wqb + zh * 262144,
        q + zb * 4194304 + zh * 524288, 512, 512, 512, 512,
        (tile >> 2) * 128, (tile & 3) * 128, 1.0f, nullptr, nullptr);
  } else if (job == 1) {
    gemm_body<bf16, 0>(As, Bs, stb + zb * 524288, wkb + zh * 262144,
        k + zb * 4194304 + zh * 524288, 512, 512, 512, 512,
        (tile >> 2) * 128, (tile & 3) * 128, 1.0f, nullptr, nullptr);
  } else {
    // vT[b,h,e,s] = Wv[h] @ states[b]^T : M=512, N=1024
    gemm_body<bf16, 0>(As, Bs, wvb + zh * 262144, stb + zb * 524288,
        vT + zb * 4194304 + zh * 524288, 512, 512, 512, 1024,
        (tile >> 3) * 128, (tile & 7) * 128, 1.0f, nullptr, nullptr);
  }
}

// sinv[row] = 1 / sum(P[row, 0..1023]); P bf16. grid 32768 x 256 thr.
__global__ __launch_bounds__(256) void rowsum_inv(
    const bf16* __restrict__ P, float* __restrict__ sinv)
{
  const int row = blockIdx.x;
  const unsigned short* prow = (const unsigned short*)(P + ((size_t)row << 10));
  const int t = threadIdx.x;
  const int lane = t & 63, w = t >> 6;
  ushort4 raw = *(const ushort4*)(prow + t * 4);
  float s = (bf2f(raw.x) + bf2f(raw.y)) + (bf2f(raw.z) + bf2f(raw.w));
#pragma unroll
  for (int off = 32; off > 0; off >>= 1) s += __shfl_xor(s, off);
  __shared__ float red[4];
  if (lane == 0) red[w] = s;
  __syncthreads();
  if (t == 0) {
    float tot = (red[0] + red[1]) + (red[2] + red[3]);
    sinv[row] = 1.0f / tot;
  }
}

// out = part0 + part1 + part2 + part3 (fp32, 2M elems). grid 2048 x 256.
__global__ __launch_bounds__(256) void reduce4(
    const float* __restrict__ part, float* __restrict__ out)
{
  const size_t i = ((size_t)blockIdx.x * 256 + threadIdx.x) * 4;
  float4 a = *(const float4*)(part + i);
  float4 b = *(const float4*)(part + 2097152 + i);
  float4 c = *(const float4*)(part + 4194304 + i);
  float4 d = *(const float4*)(part + 6291456 + i);
  float4 o;
  o.x = (a.x + b.x) + (c.x + d.x);
  o.y = (a.y + b.y) + (c.y + d.y);
  o.z = (a.z + b.z) + (c.z + d.z);
  o.w = (a.w + b.w) + (c.w + d.w);
  *(float4*)(out + i) = o;
}

extern "C" void kernel_launch(void* const* d_in, const int* in_sizes, int n_in,
                              void* d_out, int out_size, void* d_ws, size_t ws_size,
                              hipStream_t stream) {
  const float* x    = (const float*)d_in[0];   // [4,1024,512]
  const float* st   = (const float*)d_in[1];   // [4,1024,512]
  const int*   mask = (const int*)d_in[2];     // [4,1024,1024]
  const float* Wq   = (const float*)d_in[3];   // [8,512,512]
  const float* Wk   = (const float*)d_in[4];
  const float* Wv   = (const float*)d_in[5];
  const float* Wp   = (const float*)d_in[6];   // [512,4096]
  float* out = (float*)d_out;                  // [4,1024,512] fp32

  char* ws = (char*)d_ws;
  const size_t MB = 1048576;
  bf16* xb  = (bf16*)(ws);              // 4MB (2M bf16)
  bf16* stb = (bf16*)(ws + 4 * MB);
  bf16* wqb = (bf16*)(ws + 8 * MB);
  bf16* wkb = (bf16*)(ws + 12 * MB);
  bf16* wvb = (bf16*)(ws + 16 * MB);
  bf16* wpb = (bf16*)(ws + 20 * MB);
  bf16*  q   = (bf16*)(ws + 24 * MB);   // [4,8,1024,512] 32MB; ctx reuses (q dead after scores)
  bf16*  k   = (bf16*)(ws + 56 * MB);   // [4,8,1024,512] 32MB; sinv reuses (k dead after scores)
  bf16*  vT  = (bf16*)(ws + 88 * MB);   // [4,8,512,1024] 32MB; partials reuse (vT dead after ctx)
  bf16*  sc  = (bf16*)(ws + 120 * MB);  // [4,8,1024,1024] 64MB  P = exp(scores)
  bf16*  ctx = (bf16*)(ws + 24 * MB);   // [4,1024,4096] 32MB
  float* sinv = (float*)(ws + 56 * MB); // 128KB
  float* part = (float*)(ws + 88 * MB); // [4,4096,512] fp32 32MB

  dim3 blk(256);
  const float scale = 0.04419417382415922f;  // 1/sqrt(512)

  cvt6<<<dim3(2048, 6), blk, 0, stream>>>(x, st, Wq, Wk, Wv, Wp,
                                          xb, stb, wqb, wkb, wvb, wpb);

  // q/k/vT projections, fused (3072 blocks)
  qkv_kernel<<<dim3(32, 32, 3), blk, 0, stream>>>(xb, stb, wqb, wkb, wvb, q, k, vT);

  // P[b,h,l,s] = mask ? exp(scale * q.k) : 0   (M=N=1024, K=512)
  gemm_nt<bf16, 1><<<dim3(8, 8, 32), blk, 0, stream>>>(q, k, sc, 512, 512, 512, 1024,
      4194304L, 524288L, 4194304L, 524288L, 8388608L, 1048576L, scale, mask, nullptr);

  // sinv[row] = 1/rowsum(P)
  rowsum_inv<<<dim3(32768), blk, 0, stream>>>(sc, sinv);

  // ctx[b,l,h*512+e] = (P @ v) * sinv  (M=1024, N=512, K=1024)
  gemm_nt<bf16, 2><<<dim3(4, 8, 32), blk, 0, stream>>>(sc, vT, ctx, 1024, 1024, 1024, 4096,
      8388608L, 1048576L, 4194304L, 524288L, 4194304L, 512L, 1.0f, nullptr, sinv);

  // out-projection, split-K=4 into fp32 partials (M=4096, N=512, K=1024 each)
  gemm_nt<float, 0><<<dim3(4, 32, 4), blk, 0, stream>>>(ctx, wpb, part, 1024, 4096, 4096, 512,
      0L, 1024L, 0L, 1024L, 0L, 2097152L, 1.0f, nullptr, nullptr);

  // out = sum of partials
  reduce4<<<dim3(2048), blk, 0, stream>>>(part, out);
}